// Round 12
// baseline (370.921 us; speedup 1.0000x reference)
//
#include <hip/hip_runtime.h>
#include <math.h>

typedef _Float16 half8 __attribute__((ext_vector_type(8)));
typedef _Float16 half4_t __attribute__((ext_vector_type(4)));
typedef float floatx16 __attribute__((ext_vector_type(16)));
typedef float float4_t __attribute__((ext_vector_type(4)));

#define NT 128
#define NB 64
#define NC 8
#define CL 16

// ---- addrspace(1) access: force global_* (vmcnt-only) encoding ----
typedef __attribute__((address_space(1))) float gfloat;
typedef __attribute__((address_space(1))) float4_t gfloat4;
__device__ __forceinline__ float4_t gload4(const float* p) {
  return *(const gfloat4*)(unsigned long long)p;
}
__device__ __forceinline__ float gload1(const float* p) {
  return *(const gfloat*)(unsigned long long)p;
}
__device__ __forceinline__ void gstore4(float* p, float4_t v) {
  *(gfloat4*)(unsigned long long)p = v;
}
__device__ __forceinline__ void gstore1(float* p, float v) {
  *(gfloat*)(unsigned long long)p = v;
}

// element index with 8-f16 (16B) unit XOR swizzle inside a 64-f16 (128B) row (V/T)
__device__ __forceinline__ int eidx(int row, int col) {
  return row * 64 + ((((col >> 3) ^ row) & 7) << 3) + (col & 7);
}
__device__ __forceinline__ int jcolf(int j, int pblk, int hi) {
  return 32 * pblk + (j & 3) + 8 * (j >> 2) + 4 * hi;
}

// v * 2^-8 elementwise (compiles to v_pk_mul_f16)
__device__ __forceinline__ half8 hscale8(half8 v) {
  const _Float16 s = (_Float16)0.00390625f;
  half8 r;
  #pragma unroll
  for (int e = 0; e < 8; ++e) r[e] = v[e] * s;
  return r;
}

// alpha = 2^-E, alphainv = 2^E with mm = m*2^E, m in [0.5,1)  (branch-free frexp)
__device__ __forceinline__ void alpha_from_max(float mm, float& alpha, float& alphainv) {
  unsigned eb = (__float_as_uint(mm) >> 23) & 0xFFu;
  eb = (eb == 0u) ? 126u : eb;             // mm==0 or denormal -> E=0
  alpha    = __uint_as_float((253u - eb) << 23);
  alphainv = __uint_as_float((eb + 1u) << 23);
}

// LDS-only barrier (AS1 globals are vmcnt-only; lgkmcnt tracks LDS here)
#define BARX() do {                                        \
  asm volatile("s_waitcnt lgkmcnt(0)" ::: "memory");       \
  __builtin_amdgcn_s_barrier();                            \
  __builtin_amdgcn_sched_barrier(0);                       \
} while (0)

// ---------------- chunk scan: PASS3=false -> emit p_c ; PASS3=true -> emit out ----
// R12: LDS = V,T only (~320 B/thread/step through the LDS pipe vs R11's ~856);
// U hi+lo in 64 VGPRs; ONE f32 acc chain per stage (lo folded via frag pre-scale
// 2^-8); px packed f16. Target <=128 unified regs -> 4 waves/SIMD -> 2 blocks/CU.
template<bool PASS3>
__global__ __launch_bounds__(512, 4)
void qrnn_scan(const float* __restrict__ data_r, const float* __restrict__ data_i,
               const float* __restrict__ U_r, const float* __restrict__ U_i,
               const float* __restrict__ lam_p, float* __restrict__ out) {
  __shared__ __align__(16) _Float16 Vr[4096], Vi[4096];
  __shared__ __align__(16) _Float16 Tr[4096], Ti[4096];
  __shared__ __align__(16) float red[8];

  const int bx = blockIdx.x;
  const int b  = bx & (NB - 1);
  const int c  = bx >> 6;          // chunk id 0..NC-1
  const int t0 = c * CL;
  const int tid = threadIdx.x;
  const int lane = tid & 63, hi = lane >> 5, l31 = lane & 31, w = tid >> 6;
  const int grp = w >> 2, rblk = (w >> 1) & 1, pblk = w & 1;
  const int prow = 32 * rblk + l31;

  const float g = 1.0f / (1.0f + expf(-lam_p[0]));

  // ---- U fragments in REGISTERS (hi + lo*256), loaded once (L2-served) ----
  half8 Urh[4], Url[4], Uih[4], Uil[4];
  {
    const int row = 32 * pblk + l31;
    #pragma unroll
    for (int kq = 0; kq < 4; ++kq) {
      const int c0 = 16 * kq + 8 * hi;
      const float4_t a0 = gload4(U_r + row * 64 + c0);
      const float4_t a1 = gload4(U_r + row * 64 + c0 + 4);
      const float4_t b0 = gload4(U_i + row * 64 + c0);
      const float4_t b1 = gload4(U_i + row * 64 + c0 + 4);
      #pragma unroll
      for (int e = 0; e < 4; ++e) {
        _Float16 h;
        h = (_Float16)a0[e]; Urh[kq][e]     = h; Url[kq][e]     = (_Float16)((a0[e] - (float)h) * 256.0f);
        h = (_Float16)a1[e]; Urh[kq][4 + e] = h; Url[kq][4 + e] = (_Float16)((a1[e] - (float)h) * 256.0f);
        h = (_Float16)b0[e]; Uih[kq][e]     = h; Uil[kq][e]     = (_Float16)((b0[e] - (float)h) * 256.0f);
        h = (_Float16)b1[e]; Uih[kq][4 + e] = h; Uil[kq][4 + e] = (_Float16)((b1[e] - (float)h) * 256.0f);
      }
    }
  }

  // ---- initial state ----
  float rv[16];
  if constexpr (PASS3) {
    if (c == 0) {
      #pragma unroll
      for (int j = 0; j < 16; ++j)
        rv[j] = (grp == 0 && prow == jcolf(j, pblk, hi)) ? (1.0f / 64.0f) : 0.0f;
    } else {
      const float* hs = out + ((size_t)((grp ? NT : 0) + t0 + 1) * NB + b) * 4096;
      #pragma unroll
      for (int j = 0; j < 16; ++j)
        rv[j] = gload1(hs + prow * 64 + jcolf(j, pblk, hi));
    }
  } else {
    #pragma unroll
    for (int j = 0; j < 16; ++j) rv[j] = 0.0f;
  }
  {
    float ml = 0.0f;
    #pragma unroll
    for (int j = 0; j < 16; ++j) ml = fmaxf(ml, fabsf(rv[j]));
    #pragma unroll
    for (int d = 32; d >= 1; d >>= 1) ml = fmaxf(ml, __shfl_xor(ml, d, 64));
    if (lane == 0) red[w] = ml;
  }

  // x gather (f16-packed in regs): x[prow][32*pblk + 8*jj + 4*hi + e]
  const float* __restrict__ xsrc = grp ? data_i : data_r;
  const size_t xoff = (size_t)prow * 64 + 32 * pblk + 4 * hi;
  half4_t pxh[4];
  {
    const float* xp = xsrc + ((size_t)t0 * NB + b) * 4096 + xoff;
    #pragma unroll
    for (int jj = 0; jj < 4; ++jj) {
      const float4_t t = gload4(xp + 8 * jj);
      #pragma unroll
      for (int e = 0; e < 4; ++e) pxh[jj][e] = (_Float16)t[e];
    }
  }
  BARX();  // red published

  float Sig, alpha = 1.0f, alphainv = 1.0f;
  {
    float4_t r0 = *(const float4_t*)&red[0];
    float4_t r1 = *(const float4_t*)&red[4];
    float mm = fmaxf(fmaxf(fmaxf(r0[0], r0[1]), fmaxf(r0[2], r0[3])),
                     fmaxf(fmaxf(r1[0], r1[1]), fmaxf(r1[2], r1[3])));
    float sc;
    alpha_from_max(mm, sc, Sig);   // sc = 2^-E0, Sig = 2^E0
    #pragma unroll
    for (int j = 0; j < 16; ++j) rv[j] *= sc;   // normalize entry state
  }

  for (int s = 0; s < CL; ++s) {
    // ===== MIX: V^T from rv + f16 x; publish wave max (stale-1 alpha) =====
    {
      const float ga = g * alpha;
      const float kx = (1.0f - g) * alpha / Sig;
      _Float16* Vg = grp ? Vi : Vr;
      #pragma unroll
      for (int jj = 0; jj < 4; ++jj) {
        const int j0 = 32 * pblk + 8 * jj + 4 * hi;
        #pragma unroll
        for (int e = 0; e < 4; ++e) {
          const float vv = ga * rv[4 * jj + e] + kx * (float)pxh[jj][e];
          Vg[eidx(j0 + e, prow)] = (_Float16)vv;   // V^T
        }
      }
      float m0[8];
      #pragma unroll
      for (int e = 0; e < 8; ++e) m0[e] = fmaxf(fabsf(rv[e]), fabsf(rv[e + 8]));
      #pragma unroll
      for (int e = 0; e < 4; ++e) m0[e] = fmaxf(m0[e], m0[e + 4]);
      float ml = fmaxf(fmaxf(m0[0], m0[1]), fmaxf(m0[2], m0[3]));
      #pragma unroll
      for (int d = 32; d >= 1; d >>= 1) ml = fmaxf(ml, __shfl_xor(ml, d, 64));
      if (lane == 0) red[w] = ml;
    }
    BARX();  // bar1: V, red published

    // ===== REGION2: x gather s+1, out stores, alpha update, stage1 =====
    if (s + 1 < CL) {
      const float* xp = xsrc + ((size_t)(t0 + s + 1) * NB + b) * 4096 + xoff;
      #pragma unroll
      for (int jj = 0; jj < 4; ++jj) {
        const float4_t t = gload4(xp + 8 * jj);
        #pragma unroll
        for (int e = 0; e < 4; ++e) pxh[jj][e] = (_Float16)t[e];
      }
    }
    if constexpr (PASS3) {  // true h^(s) = Sig_old * rv
      if (s > 0) {
        float* oR = out + ((size_t)(t0 + s - 1) * NB + b) * 4096
                        + (grp ? (size_t)NT * NB * 4096 : 0) + (size_t)(prow * 64);
        #pragma unroll
        for (int jj = 0; jj < 4; ++jj) {
          const int j0 = 32 * pblk + 8 * jj + 4 * hi;
          float4_t ov;
          #pragma unroll
          for (int e = 0; e < 4; ++e) ov[e] = Sig * rv[4 * jj + e];
          gstore4(oR + j0, ov);
        }
      }
    }
    Sig *= alphainv;
    {
      float4_t r0 = *(const float4_t*)&red[0];
      float4_t r1 = *(const float4_t*)&red[4];
      float mm = fmaxf(fmaxf(fmaxf(r0[0], r0[1]), fmaxf(r0[2], r0[3])),
                       fmaxf(fmaxf(r1[0], r1[1]), fmaxf(r1[2], r1[3])));
      alpha_from_max(mm, alpha, alphainv);   // stale-1 alpha for next mix
    }

    // ---- stage1: t^T = V^T * U^T ; ONE acc chain, lo folded via frag*2^-8 ----
    // grp0: t_r = vr*Ur - vi*Ui -> f0=vr, f1=-vi ; grp1: t_i = vi*Ur + vr*Ui
    {
      floatx16 ah;
      #pragma unroll
      for (int j = 0; j < 16; ++j) ah[j] = 0.0f;
      #pragma unroll
      for (int kq = 0; kq < 4; ++kq) {
        const int cc = 16 * kq + 8 * hi;
        const int vo = eidx(prow, cc);
        half8 avr = *(const half8*)&Vr[vo];
        half8 avi = *(const half8*)&Vi[vo];
        half8 f0 = grp ? avi : avr;
        half8 f1 = grp ? avr : -avi;
        ah = __builtin_amdgcn_mfma_f32_32x32x16_f16(f0, Urh[kq], ah, 0, 0, 0);
        ah = __builtin_amdgcn_mfma_f32_32x32x16_f16(f1, Uih[kq], ah, 0, 0, 0);
        ah = __builtin_amdgcn_mfma_f32_32x32x16_f16(hscale8(f0), Url[kq], ah, 0, 0, 0);
        ah = __builtin_amdgcn_mfma_f32_32x32x16_f16(hscale8(f1), Uil[kq], ah, 0, 0, 0);
      }
      _Float16* Tg = grp ? Ti : Tr;
      const int tp = 32 * pblk + l31;   // T[p][r]
      #pragma unroll
      for (int jj = 0; jj < 4; ++jj) {
        const int rr0 = 32 * rblk + 8 * jj + 4 * hi;
        half4_t tv;
        #pragma unroll
        for (int e = 0; e < 4; ++e) tv[e] = (_Float16)ah[4 * jj + e];
        *(half4_t*)&Tg[eidx(tp, rr0)] = tv;
      }
    }
    BARX();  // bar2: T published

    // ---- stage2: h'^T = U * t^T -> rv ----
    // grp0: h_r = Ur*tr + Ui*ti ; grp1: h_i = Ur*ti - Ui*tr -> f1 = -tr
    {
      floatx16 ch;
      #pragma unroll
      for (int j = 0; j < 16; ++j) ch[j] = 0.0f;
      const int p2 = 32 * rblk + l31;
      #pragma unroll
      for (int kq = 0; kq < 4; ++kq) {
        const int cc = 16 * kq + 8 * hi;
        const int to = eidx(p2, cc);
        half8 btr = *(const half8*)&Tr[to];
        half8 bti = *(const half8*)&Ti[to];
        half8 f0 = grp ? bti : btr;
        half8 f1 = grp ? -btr : bti;
        ch = __builtin_amdgcn_mfma_f32_32x32x16_f16(Urh[kq], f0, ch, 0, 0, 0);
        ch = __builtin_amdgcn_mfma_f32_32x32x16_f16(Uih[kq], f1, ch, 0, 0, 0);
        ch = __builtin_amdgcn_mfma_f32_32x32x16_f16(Url[kq], hscale8(f0), ch, 0, 0, 0);
        ch = __builtin_amdgcn_mfma_f32_32x32x16_f16(Uil[kq], hscale8(f1), ch, 0, 0, 0);
      }
      #pragma unroll
      for (int j = 0; j < 16; ++j) rv[j] = ch[j];
    }
  }

  // ---- epilogue: direct store of final state (true h = Sig * rv) ----
  {
    const int trow = PASS3 ? (t0 + CL - 1) : t0;
    float* eR = out + ((size_t)trow * NB + b) * 4096
                    + (grp ? (size_t)NT * NB * 4096 : 0) + (size_t)(prow * 64);
    #pragma unroll
    for (int jj = 0; jj < 4; ++jj) {
      const int j0 = 32 * pblk + 8 * jj + 4 * hi;
      float4_t ov;
      #pragma unroll
      for (int e = 0; e < 4; ++e) ov[e] = Sig * rv[4 * jj + e];
      gstore4(eR + j0, ov);
    }
  }
}

// ---------------- K2: W = U^16 (4 LDS squarings) + 7 sequential chunk combines ----
__global__ __launch_bounds__(512, 1)
void qrnn_combine(const float* __restrict__ U_r, const float* __restrict__ U_i,
                  const float* __restrict__ lam_p, float* __restrict__ out) {
  __shared__ float Ga_r[64 * 68], Ga_i[64 * 68], Gb_r[64 * 68], Gb_i[64 * 68];
  __shared__ __align__(16) _Float16 Vr[4096], Vi[4096], Tr[4096], Ti[4096];
  __shared__ float red[8];

  const int b = blockIdx.x;
  const int tid = threadIdx.x;
  const int lane = tid & 63, hi = lane >> 5, l31 = lane & 31, w = tid >> 6;
  const int grp = w >> 2, rblk = (w >> 1) & 1, pblk = w & 1;
  const int prow = 32 * rblk + l31;

  const float g = 1.0f / (1.0f + expf(-lam_p[0]));
  const float g2 = g * g, g4 = g2 * g2, g8 = g4 * g4, g16 = g8 * g8;

  const int qr = tid >> 3, qc = (tid & 7) * 8;
  {
    *(float4_t*)&Ga_r[qr * 68 + qc]     = gload4(U_r + qr * 64 + qc);
    *(float4_t*)&Ga_r[qr * 68 + qc + 4] = gload4(U_r + qr * 64 + qc + 4);
    *(float4_t*)&Ga_i[qr * 68 + qc]     = gload4(U_i + qr * 64 + qc);
    *(float4_t*)&Ga_i[qr * 68 + qc + 4] = gload4(U_i + qr * 64 + qc + 4);
  }
  __syncthreads();

  #pragma unroll
  for (int it = 0; it < 4; ++it) {
    const float* sr = (it & 1) ? Gb_r : Ga_r;
    const float* si = (it & 1) ? Gb_i : Ga_i;
    float* dr = (it & 1) ? Ga_r : Gb_r;
    float* di = (it & 1) ? Ga_i : Gb_i;
    float cr[8], ci[8];
    #pragma unroll
    for (int e = 0; e < 8; ++e) { cr[e] = 0.0f; ci[e] = 0.0f; }
    for (int k = 0; k < 64; ++k) {
      const float ar = sr[qr * 68 + k];
      const float ai = si[qr * 68 + k];
      float4_t br0 = *(const float4_t*)&sr[k * 68 + qc];
      float4_t br1 = *(const float4_t*)&sr[k * 68 + qc + 4];
      float4_t bi0 = *(const float4_t*)&si[k * 68 + qc];
      float4_t bi1 = *(const float4_t*)&si[k * 68 + qc + 4];
      #pragma unroll
      for (int e = 0; e < 4; ++e) {
        cr[e]     += ar * br0[e] - ai * bi0[e];
        ci[e]     += ar * bi0[e] + ai * br0[e];
        cr[4 + e] += ar * br1[e] - ai * bi1[e];
        ci[4 + e] += ar * bi1[e] + ai * br1[e];
      }
    }
    float4_t s0, s1, s2, s3;
    #pragma unroll
    for (int e = 0; e < 4; ++e) { s0[e] = cr[e]; s1[e] = cr[4 + e]; s2[e] = ci[e]; s3[e] = ci[4 + e]; }
    *(float4_t*)&dr[qr * 68 + qc] = s0;  *(float4_t*)&dr[qr * 68 + qc + 4] = s1;
    *(float4_t*)&di[qr * 68 + qc] = s2;  *(float4_t*)&di[qr * 68 + qc + 4] = s3;
    __syncthreads();
  }

  half8 Wrh[4], Wrl[4], Wih[4], Wil[4];
  {
    const int row = 32 * pblk + l31;
    #pragma unroll
    for (int kq = 0; kq < 4; ++kq) {
      const int c0 = 16 * kq + 8 * hi;
      #pragma unroll
      for (int e = 0; e < 8; ++e) {
        const float wr = Ga_r[row * 68 + c0 + e];
        const float wi = Ga_i[row * 68 + c0 + e];
        _Float16 h;
        h = (_Float16)wr; Wrh[kq][e] = h; Wrl[kq][e] = (_Float16)((wr - (float)h) * 256.0f);
        h = (_Float16)wi; Wih[kq][e] = h; Wil[kq][e] = (_Float16)((wi - (float)h) * 256.0f);
      }
    }
  }

  float rv[16];
  #pragma unroll
  for (int j = 0; j < 16; ++j)
    rv[j] = (grp == 0 && prow == jcolf(j, pblk, hi)) ? (1.0f / 64.0f) : 0.0f;

  for (int c = 0; c < NC - 1; ++c) {
    float pv[16];
    {
      const float* ps = out + ((size_t)((grp ? NT : 0) + c * CL) * NB + b) * 4096;
      #pragma unroll
      for (int j = 0; j < 16; ++j) pv[j] = gload1(ps + prow * 64 + jcolf(j, pblk, hi));
    }
    float ml = 0.0f;
    #pragma unroll
    for (int j = 0; j < 16; ++j) ml = fmaxf(ml, fabsf(rv[j]));
    #pragma unroll
    for (int d = 32; d >= 1; d >>= 1) ml = fmaxf(ml, __shfl_xor(ml, d, 64));
    if (lane == 0) red[w] = ml;
    __syncthreads();
    float mm = red[0];
    #pragma unroll
    for (int i = 1; i < 8; ++i) mm = fmaxf(mm, red[i]);
    float al, alinv;
    alpha_from_max(mm, al, alinv);
    const float fE = g16 * alinv;

    {
      _Float16* Vg = grp ? Vi : Vr;
      #pragma unroll
      for (int j = 0; j < 16; ++j)
        Vg[eidx(jcolf(j, pblk, hi), prow)] = (_Float16)(al * rv[j]);
    }
    __syncthreads();

    {
      floatx16 ah;
      #pragma unroll
      for (int j = 0; j < 16; ++j) ah[j] = 0.0f;
      const int rrow = 32 * rblk + l31;
      #pragma unroll
      for (int kq = 0; kq < 4; ++kq) {
        const int cc = 16 * kq + 8 * hi;
        half8 avr = *(const half8*)&Vr[eidx(rrow, cc)];
        half8 avi = *(const half8*)&Vi[eidx(rrow, cc)];
        half8 f0 = grp ? avi : avr;
        half8 f1 = grp ? avr : -avi;
        ah = __builtin_amdgcn_mfma_f32_32x32x16_f16(f0, Wrh[kq], ah, 0, 0, 0);
        ah = __builtin_amdgcn_mfma_f32_32x32x16_f16(f1, Wih[kq], ah, 0, 0, 0);
        ah = __builtin_amdgcn_mfma_f32_32x32x16_f16(hscale8(f0), Wrl[kq], ah, 0, 0, 0);
        ah = __builtin_amdgcn_mfma_f32_32x32x16_f16(hscale8(f1), Wil[kq], ah, 0, 0, 0);
      }
      _Float16* Tg = grp ? Ti : Tr;
      const int tp = 32 * pblk + l31;
      #pragma unroll
      for (int jj = 0; jj < 4; ++jj) {
        const int rr0 = 32 * rblk + 8 * jj + 4 * hi;
        half4_t tv;
        #pragma unroll
        for (int e = 0; e < 4; ++e) tv[e] = (_Float16)ah[4 * jj + e];
        *(half4_t*)&Tg[eidx(tp, rr0)] = tv;
      }
    }
    __syncthreads();

    {
      floatx16 ch;
      #pragma unroll
      for (int j = 0; j < 16; ++j) ch[j] = 0.0f;
      const int p2 = 32 * rblk + l31;
      #pragma unroll
      for (int kq = 0; kq < 4; ++kq) {
        const int cc = 16 * kq + 8 * hi;
        half8 btr = *(const half8*)&Tr[eidx(p2, cc)];
        half8 bti = *(const half8*)&Ti[eidx(p2, cc)];
        half8 f0 = grp ? bti : btr;
        half8 f1 = grp ? -btr : bti;
        ch = __builtin_amdgcn_mfma_f32_32x32x16_f16(Wrh[kq], f0, ch, 0, 0, 0);
        ch = __builtin_amdgcn_mfma_f32_32x32x16_f16(Wih[kq], f1, ch, 0, 0, 0);
        ch = __builtin_amdgcn_mfma_f32_32x32x16_f16(Wrl[kq], hscale8(f0), ch, 0, 0, 0);
        ch = __builtin_amdgcn_mfma_f32_32x32x16_f16(Wil[kq], hscale8(f1), ch, 0, 0, 0);
      }
      #pragma unroll
      for (int j = 0; j < 16; ++j) rv[j] = fE * ch[j] + pv[j];
    }
    {
      float* hs = out + ((size_t)((grp ? NT : 0) + (c + 1) * CL + 1) * NB + b) * 4096;
      #pragma unroll
      for (int j = 0; j < 16; ++j) gstore1(hs + prow * 64 + jcolf(j, pblk, hi), rv[j]);
    }
    __syncthreads();
  }
}

extern "C" void kernel_launch(void* const* d_in, const int* in_sizes, int n_in,
                              void* d_out, int out_size, void* d_ws, size_t ws_size,
                              hipStream_t stream) {
  (void)in_sizes; (void)n_in; (void)out_size; (void)d_ws; (void)ws_size;
  const float* dr = (const float*)d_in[0];
  const float* di = (const float*)d_in[1];
  const float* ur = (const float*)d_in[2];
  const float* ui = (const float*)d_in[3];
  const float* lm = (const float*)d_in[4];
  float* o = (float*)d_out;
  qrnn_scan<false><<<dim3(NB * NC), dim3(512), 0, stream>>>(dr, di, ur, ui, lm, o);
  qrnn_combine<<<dim3(NB), dim3(512), 0, stream>>>(ur, ui, lm, o);
  qrnn_scan<true><<<dim3(NB * NC), dim3(512), 0, stream>>>(dr, di, ur, ui, lm, o);
}